// Round 7
// baseline (69.717 us; speedup 1.0000x reference)
//
#include <hip/hip_runtime.h>

// KernelExpansion: out[m] = sum_n sigma^2 * w[n] * exp(-0.5*||s_n - x_m||^2 / l^2)
// Round-7: software-pipelined MFMA path.
//  r6 diagnosis: iteration period ~6350 cyc vs ~333 cyc VALU-busy -> unhidden
//  L2 latency on the serial chain load(ah,al,wq) -> 12 MFMA -> 16 exp2.
//  exp2 measures ~16 cyc/wave64 -> whole-kernel exp2 floor ~13-16 us.
//  Changes: (1) register double-buffer prefetch of next tile's ah/al/wq
//  (pointer-stepped; last-iter over-read stays inside d_ws, values dead);
//  (2) __launch_bounds__(256,8) pins VGPR<=64 (8 waves/SIMD);
//  (3) prep_x+prep_s fused into one prep_all kernel (one less launch).
// C/D layout (verified r4 pass): acc[i] -> n-row q*4+i, m-col r.

#define LOG2E_F 1.4426950408889634f

typedef __attribute__((ext_vector_type(8))) short bf16x8;   // 8 bf16 = 4 VGPRs
typedef __attribute__((ext_vector_type(4))) float f32x4;
typedef float v2f_ __attribute__((ext_vector_type(2)));

constexpr int D      = 24;
constexpr int KP     = 32;   // padded K (cols 24..31 zero)
constexpr int TILES  = 4;    // 16-col tiles per wave -> 64 m per wave
constexpr int NSPLIT = 32;   // n-chunks; waves = (M/64)*NSPLIT = 8192 = capacity
constexpr int TPB    = 256;

__device__ inline unsigned short f32_to_bf16_rne(float f) {
    unsigned u = __builtin_bit_cast(unsigned, f);
    u += 0x7fffu + ((u >> 16) & 1u);
    return (unsigned short)(u >> 16);
}
__device__ inline float bf16_to_f32(unsigned short h) {
    unsigned u = ((unsigned)h) << 16;
    return __builtin_bit_cast(float, u);
}

// ---- fused setup:
//  i < M: x -> (x_hi, x_lo bf16 [M][32]), cx[m] = c2*||x||^2 (log2 units)
//  else : samples -> (m2c2*s) hi/lo bf16 [N][32]; w'[n] = sg^2 w_n 2^{c2||s||^2}
__global__ void prep_all(const float* __restrict__ x, const float* __restrict__ s,
                         const float* __restrict__ weights,
                         const float* __restrict__ sigma_p, const float* __restrict__ length_p,
                         unsigned short* __restrict__ xhi, unsigned short* __restrict__ xlo,
                         float* __restrict__ cx,
                         unsigned short* __restrict__ shi, unsigned short* __restrict__ slo,
                         float* __restrict__ wp, int M, int N) {
    int i = blockIdx.x * blockDim.x + threadIdx.x;
    float l  = length_p[0];
    float c2 = -0.5f * LOG2E_F / (l * l);
    if (i < M) {
        const float* xr = x + (size_t)i * D;
        unsigned short hi[KP], lo[KP];
        float ssq = 0.f;
#pragma unroll
        for (int d = 0; d < D; ++d) {
            float v = xr[d];
            ssq = fmaf(v, v, ssq);
            unsigned short h = f32_to_bf16_rne(v);
            hi[d] = h;
            lo[d] = f32_to_bf16_rne(v - bf16_to_f32(h));
        }
#pragma unroll
        for (int d = D; d < KP; ++d) { hi[d] = 0; lo[d] = 0; }
#pragma unroll
        for (int q = 0; q < KP / 8; ++q) {
            bf16x8 vh, vl;
#pragma unroll
            for (int j = 0; j < 8; ++j) { vh[j] = (short)hi[q*8+j]; vl[j] = (short)lo[q*8+j]; }
            *reinterpret_cast<bf16x8*>(xhi + (size_t)i * KP + q * 8) = vh;
            *reinterpret_cast<bf16x8*>(xlo + (size_t)i * KP + q * 8) = vl;
        }
        cx[i] = c2 * ssq;
    } else if (i < M + N) {
        int n = i - M;
        float sg   = sigma_p[0];
        float m2c2 = -2.f * c2;               // log2e / l^2
        const float* sr = s + (size_t)n * D;
        unsigned short hi[KP], lo[KP];
        float ssq = 0.f;
#pragma unroll
        for (int d = 0; d < D; ++d) {
            float v = sr[d];
            ssq = fmaf(v, v, ssq);
            float vs = m2c2 * v;              // pre-scale so acc = exp2 argument
            unsigned short h = f32_to_bf16_rne(vs);
            hi[d] = h;
            lo[d] = f32_to_bf16_rne(vs - bf16_to_f32(h));
        }
#pragma unroll
        for (int d = D; d < KP; ++d) { hi[d] = 0; lo[d] = 0; }
#pragma unroll
        for (int q = 0; q < KP / 8; ++q) {
            bf16x8 vh, vl;
#pragma unroll
            for (int j = 0; j < 8; ++j) { vh[j] = (short)hi[q*8+j]; vl[j] = (short)lo[q*8+j]; }
            *reinterpret_cast<bf16x8*>(shi + (size_t)n * KP + q * 8) = vh;
            *reinterpret_cast<bf16x8*>(slo + (size_t)n * KP + q * 8) = vl;
        }
        wp[n] = sg * sg * weights[n] * __builtin_amdgcn_exp2f(c2 * ssq);
    }
}

// ---- main: each wave owns 4 column-tiles (64 m) x one n-chunk, software-pipelined.
__global__ __launch_bounds__(TPB, 8) void ke_mfma(
    const unsigned short* __restrict__ xhi, const unsigned short* __restrict__ xlo,
    const unsigned short* __restrict__ shi, const unsigned short* __restrict__ slo,
    const float* __restrict__ wp, const float* __restrict__ cx,
    float* __restrict__ out, int M, int N) {
    int lane = threadIdx.x & 63;
    int wave = blockIdx.x * (TPB / 64) + (threadIdx.x >> 6);
    int MG   = M / (TILES * 16);          // column-groups of 64
    int ns   = wave / MG;
    int mg   = wave - ns * MG;
    int m0   = mg * (TILES * 16);
    int r    = lane & 15;
    int q    = lane >> 4;

    // B fragments (x) for 4 column-tiles, pinned for the whole n-loop.
    bf16x8 bh[TILES], bl[TILES];
#pragma unroll
    for (int j = 0; j < TILES; ++j) {
        size_t xo = ((size_t)(m0 + j * 16 + r)) * KP + q * 8;
        bh[j] = *reinterpret_cast<const bf16x8*>(xhi + xo);
        bl[j] = *reinterpret_cast<const bf16x8*>(xlo + xo);
    }
#pragma unroll
    for (int j = 0; j < TILES; ++j) {
        asm("" : "+v"(bh[j]));
        asm("" : "+v"(bl[j]));
    }

    int per = (N / 16) / NSPLIT;          // 16
    int t0  = ns * per;

    // pointer-stepped tile streams
    const unsigned short* shp = shi + ((size_t)(t0 * 16 + r)) * KP + q * 8;
    const unsigned short* slp = slo + ((size_t)(t0 * 16 + r)) * KP + q * 8;
    const float*          wpp = wp + t0 * 16 + q * 4;

    bf16x8 ah = *reinterpret_cast<const bf16x8*>(shp);
    bf16x8 al = *reinterpret_cast<const bf16x8*>(slp);
    f32x4  wq = *reinterpret_cast<const f32x4*>(wpp);

    float p[TILES] = {0.f, 0.f, 0.f, 0.f};
#pragma unroll 2
    for (int t = 0; t < per; ++t) {
        // issue next tile's loads first (dead on last iter; over-read stays in d_ws)
        shp += 16 * KP; slp += 16 * KP; wpp += 16;
        bf16x8 ah_n = *reinterpret_cast<const bf16x8*>(shp);
        bf16x8 al_n = *reinterpret_cast<const bf16x8*>(slp);
        f32x4  wq_n = *reinterpret_cast<const f32x4*>(wpp);

        f32x4 acc[TILES];
#pragma unroll
        for (int j = 0; j < TILES; ++j) {
            f32x4 z = {0.f, 0.f, 0.f, 0.f};
            acc[j] = __builtin_amdgcn_mfma_f32_16x16x32_bf16(ah, bh[j], z, 0, 0, 0);
        }
#pragma unroll
        for (int j = 0; j < TILES; ++j)
            acc[j] = __builtin_amdgcn_mfma_f32_16x16x32_bf16(al, bh[j], acc[j], 0, 0, 0);
#pragma unroll
        for (int j = 0; j < TILES; ++j)
            acc[j] = __builtin_amdgcn_mfma_f32_16x16x32_bf16(ah, bl[j], acc[j], 0, 0, 0);
#pragma unroll
        for (int j = 0; j < TILES; ++j) {
            float pj = p[j];
            pj = fmaf(wq[0], __builtin_amdgcn_exp2f(acc[j][0]), pj);
            pj = fmaf(wq[1], __builtin_amdgcn_exp2f(acc[j][1]), pj);
            pj = fmaf(wq[2], __builtin_amdgcn_exp2f(acc[j][2]), pj);
            pj = fmaf(wq[3], __builtin_amdgcn_exp2f(acc[j][3]), pj);
            p[j] = pj;
        }
        ah = ah_n; al = al_n; wq = wq_n;
    }
    // reduce over the 4 q-quarters (column r fixed)
#pragma unroll
    for (int j = 0; j < TILES; ++j) {
        p[j] += __shfl_xor(p[j], 16, 64);
        p[j] += __shfl_xor(p[j], 32, 64);
    }
    if (lane < 16) {
#pragma unroll
        for (int j = 0; j < TILES; ++j) {
            int m = m0 + j * 16 + r;
            atomicAdd(&out[m], p[j] * __builtin_amdgcn_exp2f(cx[m]));
        }
    }
}

// ---- fallback: fp32 VALU kernel (no workspace needed)
constexpr int MPT  = 2;
constexpr int MBLK = TPB * MPT;

__global__ __launch_bounds__(TPB) void ke_plain(
    const float* __restrict__ x, const float* __restrict__ samples,
    const float* __restrict__ weights, const float* __restrict__ sigma_p,
    const float* __restrict__ length_p, float* __restrict__ out,
    int M, int N, int nsplit, int chunk) {
    int mb = blockIdx.x / nsplit;
    int ns = blockIdx.x - mb * nsplit;
    int t  = threadIdx.x;
    int m0 = mb * MBLK + t;
    int m1 = m0 + TPB;
    int m0c = (m0 < M) ? m0 : 0;
    int m1c = (m1 < M) ? m1 : 0;

    v2f_ xaq[D / 2], xbq[D / 2];
    const v2f_* xp0 = reinterpret_cast<const v2f_*>(x + (size_t)m0c * D);
    const v2f_* xp1 = reinterpret_cast<const v2f_*>(x + (size_t)m1c * D);
#pragma unroll
    for (int qq = 0; qq < D / 2; ++qq) { xaq[qq] = xp0[qq]; xbq[qq] = xp1[qq]; }
#pragma unroll
    for (int qq = 0; qq < D / 2; ++qq) { asm("" : "+v"(xaq[qq])); asm("" : "+v"(xbq[qq])); }

    float l   = length_p[0];
    float c   = -0.5f * LOG2E_F / (l * l);
    float m2c = -2.f * c;
    float sg  = sigma_p[0];
    float sg2 = sg * sg;

    v2f_ qa = {0.f, 0.f}, qb = {0.f, 0.f};
#pragma unroll
    for (int qq = 0; qq < D / 2; ++qq) {
        qa = __builtin_elementwise_fma(xaq[qq], xaq[qq], qa);
        qb = __builtin_elementwise_fma(xbq[qq], xbq[qq], qb);
    }
    float cxa = c * (qa.x + qa.y);
    float cxb = c * (qb.x + qb.y);

    float acc0 = 0.f, acc1 = 0.f;
    int n0 = ns * chunk;
    int n1 = n0 + chunk;
    if (n1 > N) n1 = N;
#pragma unroll 2
    for (int n = n0; n < n1; ++n) {
        const v2f_* s2 = reinterpret_cast<const v2f_*>(samples + (size_t)n * D);
        v2f_ da = {0.f, 0.f}, db = {0.f, 0.f}, sq = {0.f, 0.f};
#pragma unroll
        for (int qq = 0; qq < D / 2; ++qq) {
            v2f_ sv = s2[qq];
            sq = __builtin_elementwise_fma(sv, sv, sq);
            da = __builtin_elementwise_fma(sv, xaq[qq], da);
            db = __builtin_elementwise_fma(sv, xbq[qq], db);
        }
        float cn = c * (sq.x + sq.y);
        float wn = sg2 * weights[n];
        float e0 = fmaf(m2c, da.x + da.y, cn);
        float e1 = fmaf(m2c, db.x + db.y, cn);
        acc0 = fmaf(wn, __builtin_amdgcn_exp2f(e0), acc0);
        acc1 = fmaf(wn, __builtin_amdgcn_exp2f(e1), acc1);
    }
    if (m0 < M) atomicAdd(&out[m0], acc0 * __builtin_amdgcn_exp2f(cxa));
    if (m1 < M) atomicAdd(&out[m1], acc1 * __builtin_amdgcn_exp2f(cxb));
}

extern "C" void kernel_launch(void* const* d_in, const int* in_sizes, int n_in,
                              void* d_out, int out_size, void* d_ws, size_t ws_size,
                              hipStream_t stream) {
    const float* x       = (const float*)d_in[0];
    const float* samples = (const float*)d_in[1];
    const float* weights = (const float*)d_in[2];
    const float* sigma_p = (const float*)d_in[3];
    const float* length_p= (const float*)d_in[4];
    float* out = (float*)d_out;

    int M = in_sizes[0] / D;
    int N = in_sizes[1] / D;

    hipMemsetAsync(out, 0, (size_t)out_size * sizeof(float), stream);

    // workspace layout (bytes)
    size_t xhi_off = 0;
    size_t xlo_off = xhi_off + (size_t)M * KP * 2;
    size_t shi_off = xlo_off + (size_t)M * KP * 2;
    size_t slo_off = shi_off + (size_t)N * KP * 2;
    size_t wp_off  = slo_off + (size_t)N * KP * 2;
    size_t cx_off  = wp_off + (size_t)N * 4;
    size_t need    = cx_off + (size_t)M * 4;

    int  MT = TILES * 16;  // 64 m per wave
    bool mfma_ok = ws_size >= need &&
                   (M % MT) == 0 && ((M / MT) % (TPB / 64)) == 0 &&
                   (N % 16) == 0 && ((N / 16) % NSPLIT) == 0;

    if (mfma_ok) {
        char* ws = (char*)d_ws;
        unsigned short* xhi = (unsigned short*)(ws + xhi_off);
        unsigned short* xlo = (unsigned short*)(ws + xlo_off);
        unsigned short* shi = (unsigned short*)(ws + shi_off);
        unsigned short* slo = (unsigned short*)(ws + slo_off);
        float* wp = (float*)(ws + wp_off);
        float* cx = (float*)(ws + cx_off);

        prep_all<<<dim3((M + N + TPB - 1) / TPB), dim3(TPB), 0, stream>>>(
            x, samples, weights, sigma_p, length_p, xhi, xlo, cx, shi, slo, wp, M, N);

        int waves  = (M / MT) * NSPLIT;           // 8192
        int blocks = waves / (TPB / 64);          // 2048
        ke_mfma<<<dim3(blocks), dim3(TPB), 0, stream>>>(
            xhi, xlo, shi, slo, wp, cx, out, M, N);
    } else {
        int mbcnt  = (M + MBLK - 1) / MBLK;
        int nsplit = 2048 / (mbcnt > 0 ? mbcnt : 1);
        if (nsplit < 1) nsplit = 1;
        if (nsplit > N) nsplit = N;
        int chunk = (N + nsplit - 1) / nsplit;
        ke_plain<<<dim3(mbcnt * nsplit), dim3(TPB), 0, stream>>>(
            x, samples, weights, sigma_p, length_p, out, M, N, nsplit, chunk);
    }
}

// Round 8
// 36.884 us; speedup vs baseline: 1.8902x; 1.8902x over previous
//
#include <hip/hip_runtime.h>

// KernelExpansion: out[m] = sum_n sigma^2 * w[n] * exp(-0.5*||s_n - x_m||^2 / l^2)
// Round-8: software pipeline with a sane register budget + K-pad constant folding.
//  r7 failure: launch_bounds(256,8) forced VGPR<=64, prefetch set needs ~85 ->
//  scratch spill (WRITE_SIZE 2MB->18MB). Fix: launch_bounds(256,4) (<=128).
//  New: all scalar terms folded into MFMA K-pad columns (24..31 were zero):
//    A[n,24]=lw_hi, A[n,25]=lw_lo (lw = log2(sg^2 w_n) + c2||s||^2), B[.,24]=B[.,25]=1
//    B[m,26]=cx_hi, B[m,27]=cx_lo (cx = c2||x||^2),                  A[.,26]=A[.,27]=1
//  -> acc IS the full exp2 argument; epilogue p += exp2(acc); no wq stream,
//  no wp/cx arrays, no tail exp2. prep also zeroes out[] (memset launch dropped).
// C/D layout (verified r4 pass): acc[i] -> n-row q*4+i, m-col r.

#define LOG2E_F 1.4426950408889634f

typedef __attribute__((ext_vector_type(8))) short bf16x8;   // 8 bf16 = 4 VGPRs
typedef __attribute__((ext_vector_type(4))) float f32x4;
typedef float v2f_ __attribute__((ext_vector_type(2)));

constexpr int D      = 24;
constexpr int KP     = 32;   // padded K; 24-27 carry folded constants, 28-31 zero
constexpr int TILES  = 4;    // 16-col tiles per wave -> 64 m per wave
constexpr int NSPLIT = 32;   // n-chunks; waves = (M/64)*NSPLIT = 8192
constexpr int TPB    = 256;

__device__ inline unsigned short f32_to_bf16_rne(float f) {
    unsigned u = __builtin_bit_cast(unsigned, f);
    u += 0x7fffu + ((u >> 16) & 1u);
    return (unsigned short)(u >> 16);
}
__device__ inline float bf16_to_f32(unsigned short h) {
    unsigned u = ((unsigned)h) << 16;
    return __builtin_bit_cast(float, u);
}

constexpr unsigned short BF16_ONE = 0x3F80;

// ---- fused setup (also zeroes out[] for the atomic accumulation):
__global__ void prep_all(const float* __restrict__ x, const float* __restrict__ s,
                         const float* __restrict__ weights,
                         const float* __restrict__ sigma_p, const float* __restrict__ length_p,
                         unsigned short* __restrict__ xhi, unsigned short* __restrict__ xlo,
                         unsigned short* __restrict__ shi, unsigned short* __restrict__ slo,
                         float* __restrict__ out, int M, int N) {
    int i = blockIdx.x * blockDim.x + threadIdx.x;
    float l  = length_p[0];
    float c2 = -0.5f * LOG2E_F / (l * l);
    if (i < M) {
        out[i] = 0.f;
        const float* xr = x + (size_t)i * D;
        unsigned short hi[KP], lo[KP];
        float ssq = 0.f;
#pragma unroll
        for (int d = 0; d < D; ++d) {
            float v = xr[d];
            ssq = fmaf(v, v, ssq);
            unsigned short h = f32_to_bf16_rne(v);
            hi[d] = h;
            lo[d] = f32_to_bf16_rne(v - bf16_to_f32(h));
        }
#pragma unroll
        for (int d = D; d < KP; ++d) { hi[d] = 0; lo[d] = 0; }
        // k=24,25: B-side ones (multiply A's lw_hi/lw_lo)
        hi[24] = BF16_ONE; hi[25] = BF16_ONE;
        // k=26,27: cx = c2*||x||^2 as hi/lo (A-side carries ones there)
        float cxv = c2 * ssq;
        unsigned short chi = f32_to_bf16_rne(cxv);
        hi[26] = chi;
        hi[27] = f32_to_bf16_rne(cxv - bf16_to_f32(chi));
#pragma unroll
        for (int q = 0; q < KP / 8; ++q) {
            bf16x8 vh, vl;
#pragma unroll
            for (int j = 0; j < 8; ++j) { vh[j] = (short)hi[q*8+j]; vl[j] = (short)lo[q*8+j]; }
            *reinterpret_cast<bf16x8*>(xhi + (size_t)i * KP + q * 8) = vh;
            *reinterpret_cast<bf16x8*>(xlo + (size_t)i * KP + q * 8) = vl;
        }
    } else if (i < M + N) {
        int n = i - M;
        float sg   = sigma_p[0];
        float m2c2 = -2.f * c2;               // log2e / l^2
        const float* sr = s + (size_t)n * D;
        unsigned short hi[KP], lo[KP];
        float ssq = 0.f;
#pragma unroll
        for (int d = 0; d < D; ++d) {
            float v = sr[d];
            ssq = fmaf(v, v, ssq);
            float vs = m2c2 * v;              // pre-scaled so acc = exp2 argument
            unsigned short h = f32_to_bf16_rne(vs);
            hi[d] = h;
            lo[d] = f32_to_bf16_rne(vs - bf16_to_f32(h));
        }
#pragma unroll
        for (int d = D; d < KP; ++d) { hi[d] = 0; lo[d] = 0; }
        // k=24,25: lw = log2(sg^2*w) + c2*||s||^2 as hi/lo (B-side carries ones)
        float lwt = __log2f(sg * sg * weights[n]) + c2 * ssq;
        lwt = fmaxf(lwt, -20000.f);           // w==0 -> finite, exp2 -> 0
        unsigned short lhi = f32_to_bf16_rne(lwt);
        hi[24] = lhi;
        hi[25] = f32_to_bf16_rne(lwt - bf16_to_f32(lhi));
        // k=26,27: A-side ones (multiply B's cx_hi/cx_lo)
        hi[26] = BF16_ONE; hi[27] = BF16_ONE;
#pragma unroll
        for (int q = 0; q < KP / 8; ++q) {
            bf16x8 vh, vl;
#pragma unroll
            for (int j = 0; j < 8; ++j) { vh[j] = (short)hi[q*8+j]; vl[j] = (short)lo[q*8+j]; }
            *reinterpret_cast<bf16x8*>(shi + (size_t)n * KP + q * 8) = vh;
            *reinterpret_cast<bf16x8*>(slo + (size_t)n * KP + q * 8) = vl;
        }
    }
}

// ---- main: each wave owns 4 column-tiles (64 m) x one n-chunk, 1-deep prefetch.
__global__ __launch_bounds__(TPB, 4) void ke_mfma(
    const unsigned short* __restrict__ xhi, const unsigned short* __restrict__ xlo,
    const unsigned short* __restrict__ shi, const unsigned short* __restrict__ slo,
    float* __restrict__ out, int M, int N) {
    int lane = threadIdx.x & 63;
    int wave = blockIdx.x * (TPB / 64) + (threadIdx.x >> 6);
    int MG   = M / (TILES * 16);          // column-groups of 64
    int ns   = wave / MG;                 // block's 4 waves share ns
    int mg   = wave - ns * MG;
    int m0   = mg * (TILES * 16);
    int r    = lane & 15;
    int q    = lane >> 4;

    // B fragments (x) for 4 column-tiles, pinned for the whole n-loop.
    bf16x8 bh[TILES], bl[TILES];
#pragma unroll
    for (int j = 0; j < TILES; ++j) {
        size_t xo = ((size_t)(m0 + j * 16 + r)) * KP + q * 8;
        bh[j] = *reinterpret_cast<const bf16x8*>(xhi + xo);
        bl[j] = *reinterpret_cast<const bf16x8*>(xlo + xo);
    }
#pragma unroll
    for (int j = 0; j < TILES; ++j) {
        asm("" : "+v"(bh[j]));
        asm("" : "+v"(bl[j]));
    }

    int per = (N / 16) / NSPLIT;          // 16
    int t0  = ns * per;

    const unsigned short* shp = shi + ((size_t)(t0 * 16 + r)) * KP + q * 8;
    const unsigned short* slp = slo + ((size_t)(t0 * 16 + r)) * KP + q * 8;

    bf16x8 ah = *reinterpret_cast<const bf16x8*>(shp);
    bf16x8 al = *reinterpret_cast<const bf16x8*>(slp);

    float p[TILES] = {0.f, 0.f, 0.f, 0.f};
    for (int t = 0; t < per; ++t) {
        // issue next tile's loads first (dead on last iter; pad keeps it in-bounds)
        shp += 16 * KP; slp += 16 * KP;
        bf16x8 ah_n = *reinterpret_cast<const bf16x8*>(shp);
        bf16x8 al_n = *reinterpret_cast<const bf16x8*>(slp);

        f32x4 acc[TILES];
#pragma unroll
        for (int j = 0; j < TILES; ++j) {
            f32x4 z = {0.f, 0.f, 0.f, 0.f};
            acc[j] = __builtin_amdgcn_mfma_f32_16x16x32_bf16(ah, bh[j], z, 0, 0, 0);
        }
#pragma unroll
        for (int j = 0; j < TILES; ++j)
            acc[j] = __builtin_amdgcn_mfma_f32_16x16x32_bf16(al, bh[j], acc[j], 0, 0, 0);
#pragma unroll
        for (int j = 0; j < TILES; ++j)
            acc[j] = __builtin_amdgcn_mfma_f32_16x16x32_bf16(ah, bl[j], acc[j], 0, 0, 0);
#pragma unroll
        for (int j = 0; j < TILES; ++j) {
            float e0 = __builtin_amdgcn_exp2f(acc[j][0]);
            float e1 = __builtin_amdgcn_exp2f(acc[j][1]);
            float e2 = __builtin_amdgcn_exp2f(acc[j][2]);
            float e3 = __builtin_amdgcn_exp2f(acc[j][3]);
            p[j] += (e0 + e1) + (e2 + e3);
        }
        ah = ah_n; al = al_n;
    }
    // reduce over the 4 q-quarters (column r fixed)
#pragma unroll
    for (int j = 0; j < TILES; ++j) {
        p[j] += __shfl_xor(p[j], 16, 64);
        p[j] += __shfl_xor(p[j], 32, 64);
    }
    if (lane < 16) {
#pragma unroll
        for (int j = 0; j < TILES; ++j)
            atomicAdd(&out[m0 + j * 16 + r], p[j]);
    }
}

// ---- fallback: fp32 VALU kernel (no workspace needed)
constexpr int MPT  = 2;
constexpr int MBLK = TPB * MPT;

__global__ __launch_bounds__(TPB) void ke_plain(
    const float* __restrict__ x, const float* __restrict__ samples,
    const float* __restrict__ weights, const float* __restrict__ sigma_p,
    const float* __restrict__ length_p, float* __restrict__ out,
    int M, int N, int nsplit, int chunk) {
    int mb = blockIdx.x / nsplit;
    int ns = blockIdx.x - mb * nsplit;
    int t  = threadIdx.x;
    int m0 = mb * MBLK + t;
    int m1 = m0 + TPB;
    int m0c = (m0 < M) ? m0 : 0;
    int m1c = (m1 < M) ? m1 : 0;

    v2f_ xaq[D / 2], xbq[D / 2];
    const v2f_* xp0 = reinterpret_cast<const v2f_*>(x + (size_t)m0c * D);
    const v2f_* xp1 = reinterpret_cast<const v2f_*>(x + (size_t)m1c * D);
#pragma unroll
    for (int qq = 0; qq < D / 2; ++qq) { xaq[qq] = xp0[qq]; xbq[qq] = xp1[qq]; }
#pragma unroll
    for (int qq = 0; qq < D / 2; ++qq) { asm("" : "+v"(xaq[qq])); asm("" : "+v"(xbq[qq])); }

    float l   = length_p[0];
    float c   = -0.5f * LOG2E_F / (l * l);
    float m2c = -2.f * c;
    float sg  = sigma_p[0];
    float sg2 = sg * sg;

    v2f_ qa = {0.f, 0.f}, qb = {0.f, 0.f};
#pragma unroll
    for (int qq = 0; qq < D / 2; ++qq) {
        qa = __builtin_elementwise_fma(xaq[qq], xaq[qq], qa);
        qb = __builtin_elementwise_fma(xbq[qq], xbq[qq], qb);
    }
    float cxa = c * (qa.x + qa.y);
    float cxb = c * (qb.x + qb.y);

    float acc0 = 0.f, acc1 = 0.f;
    int n0 = ns * chunk;
    int n1 = n0 + chunk;
    if (n1 > N) n1 = N;
#pragma unroll 2
    for (int n = n0; n < n1; ++n) {
        const v2f_* s2 = reinterpret_cast<const v2f_*>(samples + (size_t)n * D);
        v2f_ da = {0.f, 0.f}, db = {0.f, 0.f}, sq = {0.f, 0.f};
#pragma unroll
        for (int qq = 0; qq < D / 2; ++qq) {
            v2f_ sv = s2[qq];
            sq = __builtin_elementwise_fma(sv, sv, sq);
            da = __builtin_elementwise_fma(sv, xaq[qq], da);
            db = __builtin_elementwise_fma(sv, xbq[qq], db);
        }
        float cn = c * (sq.x + sq.y);
        float wn = sg2 * weights[n];
        float e0 = fmaf(m2c, da.x + da.y, cn);
        float e1 = fmaf(m2c, db.x + db.y, cn);
        acc0 = fmaf(wn, __builtin_amdgcn_exp2f(e0), acc0);
        acc1 = fmaf(wn, __builtin_amdgcn_exp2f(e1), acc1);
    }
    if (m0 < M) atomicAdd(&out[m0], acc0 * __builtin_amdgcn_exp2f(cxa));
    if (m1 < M) atomicAdd(&out[m1], acc1 * __builtin_amdgcn_exp2f(cxb));
}

extern "C" void kernel_launch(void* const* d_in, const int* in_sizes, int n_in,
                              void* d_out, int out_size, void* d_ws, size_t ws_size,
                              hipStream_t stream) {
    const float* x       = (const float*)d_in[0];
    const float* samples = (const float*)d_in[1];
    const float* weights = (const float*)d_in[2];
    const float* sigma_p = (const float*)d_in[3];
    const float* length_p= (const float*)d_in[4];
    float* out = (float*)d_out;

    int M = in_sizes[0] / D;
    int N = in_sizes[1] / D;

    // workspace layout (bytes): xhi, xlo, shi, slo + prefetch-overread pad
    size_t xhi_off = 0;
    size_t xlo_off = xhi_off + (size_t)M * KP * 2;
    size_t shi_off = xlo_off + (size_t)M * KP * 2;
    size_t slo_off = shi_off + (size_t)N * KP * 2;
    size_t need    = slo_off + (size_t)N * KP * 2 + (size_t)16 * KP * 2;

    int  MT = TILES * 16;  // 64 m per wave
    bool mfma_ok = ws_size >= need &&
                   (M % MT) == 0 && ((M / MT) % (TPB / 64)) == 0 &&
                   (N % 16) == 0 && ((N / 16) % NSPLIT) == 0 && out_size >= M;

    if (mfma_ok) {
        char* ws = (char*)d_ws;
        unsigned short* xhi = (unsigned short*)(ws + xhi_off);
        unsigned short* xlo = (unsigned short*)(ws + xlo_off);
        unsigned short* shi = (unsigned short*)(ws + shi_off);
        unsigned short* slo = (unsigned short*)(ws + slo_off);

        prep_all<<<dim3((M + N + TPB - 1) / TPB), dim3(TPB), 0, stream>>>(
            x, samples, weights, sigma_p, length_p, xhi, xlo, shi, slo, out, M, N);

        int waves  = (M / MT) * NSPLIT;           // 8192
        int blocks = waves / (TPB / 64);          // 2048
        ke_mfma<<<dim3(blocks), dim3(TPB), 0, stream>>>(
            xhi, xlo, shi, slo, out, M, N);
    } else {
        hipMemsetAsync(out, 0, (size_t)out_size * sizeof(float), stream);
        int mbcnt  = (M + MBLK - 1) / MBLK;
        int nsplit = 2048 / (mbcnt > 0 ? mbcnt : 1);
        if (nsplit < 1) nsplit = 1;
        if (nsplit > N) nsplit = N;
        int chunk = (N + nsplit - 1) / nsplit;
        ke_plain<<<dim3(mbcnt * nsplit), dim3(TPB), 0, stream>>>(
            x, samples, weights, sigma_p, length_p, out, M, N, nsplit, chunk);
    }
}

// Round 9
// 35.413 us; speedup vs baseline: 1.9687x; 1.0415x over previous
//
#include <hip/hip_runtime.h>

// KernelExpansion: out[m] = sum_n sigma^2 * w[n] * exp(-0.5*||s_n - x_m||^2 / l^2)
// Round-9: 8 waves/SIMD by register-budget design.
//  r8 was launch_bounds(256,4): ~4 waves/SIMD, latency-limited (~30us main vs
//  ~10us VALU floor). r7's 8-wave attempt spilled (prefetch + acc[4] ~ 100 VGPR
//  under a 64 cap). This round: working set engineered to ~58 VGPR:
//   - per-tile fused epilogue (3 MFMA -> 4 exp2 -> p[j]) => one live acc (4 reg)
//   - no manual prefetch (8-wave TLP hides L1/L2 latency instead)
//   - t-loop pinned unroll 1 (stop compiler re-inflating live ranges)
//  K-pad constant folding kept from r8: acc IS the exp2 argument.
//    A[n,24]=lw_hi, A[n,25]=lw_lo (lw = log2(sg^2 w_n)+c2||s||^2), B[.,24]=B[.,25]=1
//    B[m,26]=cx_hi, B[m,27]=cx_lo (cx = c2||x||^2),                A[.,26]=A[.,27]=1
// C/D layout (verified r4 pass): acc[i] -> n-row q*4+i, m-col r.

#define LOG2E_F 1.4426950408889634f

typedef __attribute__((ext_vector_type(8))) short bf16x8;   // 8 bf16 = 4 VGPRs
typedef __attribute__((ext_vector_type(4))) float f32x4;
typedef float v2f_ __attribute__((ext_vector_type(2)));

constexpr int D       = 24;
constexpr int KP      = 32;   // padded K; 24-27 carry folded constants, 28-31 zero
constexpr int TILES   = 4;    // 16-col tiles per wave -> 64 m per wave
constexpr int NSPLIT  = 32;   // n-chunks; waves = (M/64)*NSPLIT = 8192
constexpr int TPB     = 256;
constexpr int TPB_PRE = 64;

__device__ inline unsigned short f32_to_bf16_rne(float f) {
    unsigned u = __builtin_bit_cast(unsigned, f);
    u += 0x7fffu + ((u >> 16) & 1u);
    return (unsigned short)(u >> 16);
}
__device__ inline float bf16_to_f32(unsigned short h) {
    unsigned u = ((unsigned)h) << 16;
    return __builtin_bit_cast(float, u);
}

constexpr unsigned short BF16_ONE = 0x3F80;

// ---- fused setup (also zeroes out[] for the atomic accumulation):
__global__ void prep_all(const float* __restrict__ x, const float* __restrict__ s,
                         const float* __restrict__ weights,
                         const float* __restrict__ sigma_p, const float* __restrict__ length_p,
                         unsigned short* __restrict__ xhi, unsigned short* __restrict__ xlo,
                         unsigned short* __restrict__ shi, unsigned short* __restrict__ slo,
                         float* __restrict__ out, int M, int N) {
    int i = blockIdx.x * blockDim.x + threadIdx.x;
    float l  = length_p[0];
    float c2 = -0.5f * LOG2E_F / (l * l);
    if (i < M) {
        out[i] = 0.f;
        const float* xr = x + (size_t)i * D;
        unsigned short hi[KP], lo[KP];
        float ssq = 0.f;
#pragma unroll
        for (int d = 0; d < D; ++d) {
            float v = xr[d];
            ssq = fmaf(v, v, ssq);
            unsigned short h = f32_to_bf16_rne(v);
            hi[d] = h;
            lo[d] = f32_to_bf16_rne(v - bf16_to_f32(h));
        }
#pragma unroll
        for (int d = D; d < KP; ++d) { hi[d] = 0; lo[d] = 0; }
        hi[24] = BF16_ONE; hi[25] = BF16_ONE;          // multiply A's lw terms
        float cxv = c2 * ssq;
        unsigned short chi = f32_to_bf16_rne(cxv);
        hi[26] = chi;
        hi[27] = f32_to_bf16_rne(cxv - bf16_to_f32(chi));
#pragma unroll
        for (int q = 0; q < KP / 8; ++q) {
            bf16x8 vh, vl;
#pragma unroll
            for (int j = 0; j < 8; ++j) { vh[j] = (short)hi[q*8+j]; vl[j] = (short)lo[q*8+j]; }
            *reinterpret_cast<bf16x8*>(xhi + (size_t)i * KP + q * 8) = vh;
            *reinterpret_cast<bf16x8*>(xlo + (size_t)i * KP + q * 8) = vl;
        }
    } else if (i < M + N) {
        int n = i - M;
        float sg   = sigma_p[0];
        float m2c2 = -2.f * c2;               // log2e / l^2
        const float* sr = s + (size_t)n * D;
        unsigned short hi[KP], lo[KP];
        float ssq = 0.f;
#pragma unroll
        for (int d = 0; d < D; ++d) {
            float v = sr[d];
            ssq = fmaf(v, v, ssq);
            float vs = m2c2 * v;              // pre-scaled so acc = exp2 argument
            unsigned short h = f32_to_bf16_rne(vs);
            hi[d] = h;
            lo[d] = f32_to_bf16_rne(vs - bf16_to_f32(h));
        }
#pragma unroll
        for (int d = D; d < KP; ++d) { hi[d] = 0; lo[d] = 0; }
        float lwt = __log2f(sg * sg * weights[n]) + c2 * ssq;
        lwt = fmaxf(lwt, -20000.f);           // w==0 -> finite, exp2 -> 0
        unsigned short lhi = f32_to_bf16_rne(lwt);
        hi[24] = lhi;
        hi[25] = f32_to_bf16_rne(lwt - bf16_to_f32(lhi));
        hi[26] = BF16_ONE; hi[27] = BF16_ONE;          // multiply B's cx terms
#pragma unroll
        for (int q = 0; q < KP / 8; ++q) {
            bf16x8 vh, vl;
#pragma unroll
            for (int j = 0; j < 8; ++j) { vh[j] = (short)hi[q*8+j]; vl[j] = (short)lo[q*8+j]; }
            *reinterpret_cast<bf16x8*>(shi + (size_t)n * KP + q * 8) = vh;
            *reinterpret_cast<bf16x8*>(slo + (size_t)n * KP + q * 8) = vl;
        }
    }
}

// ---- main: each wave owns 4 column-tiles (64 m) x one n-chunk.
// Working set ~58 VGPR -> 8 waves/SIMD; TLP hides load latency.
__global__ __launch_bounds__(TPB, 8) void ke_mfma(
    const unsigned short* __restrict__ xhi, const unsigned short* __restrict__ xlo,
    const unsigned short* __restrict__ shi, const unsigned short* __restrict__ slo,
    float* __restrict__ out, int M, int N) {
    int lane = threadIdx.x & 63;
    int wave = blockIdx.x * (TPB / 64) + (threadIdx.x >> 6);
    int MG   = M / (TILES * 16);          // column-groups of 64
    int ns   = wave / MG;                 // block's 4 waves share ns
    int mg   = wave - ns * MG;
    int m0   = mg * (TILES * 16);
    int r    = lane & 15;
    int q    = lane >> 4;

    // B fragments (x) for 4 column-tiles, pinned for the whole n-loop.
    bf16x8 bh[TILES], bl[TILES];
#pragma unroll
    for (int j = 0; j < TILES; ++j) {
        size_t xo = ((size_t)(m0 + j * 16 + r)) * KP + q * 8;
        bh[j] = *reinterpret_cast<const bf16x8*>(xhi + xo);
        bl[j] = *reinterpret_cast<const bf16x8*>(xlo + xo);
    }
#pragma unroll
    for (int j = 0; j < TILES; ++j) {
        asm("" : "+v"(bh[j]));
        asm("" : "+v"(bl[j]));
    }

    int per = (N / 16) / NSPLIT;          // 16
    int t0  = ns * per;

    const unsigned short* shp = shi + ((size_t)(t0 * 16 + r)) * KP + q * 8;
    const unsigned short* slp = slo + ((size_t)(t0 * 16 + r)) * KP + q * 8;

    float p[TILES] = {0.f, 0.f, 0.f, 0.f};
#pragma unroll 1
    for (int t = 0; t < per; ++t) {
        bf16x8 ah = *reinterpret_cast<const bf16x8*>(shp);
        bf16x8 al = *reinterpret_cast<const bf16x8*>(slp);
        shp += 16 * KP; slp += 16 * KP;
#pragma unroll
        for (int j = 0; j < TILES; ++j) {
            f32x4 z = {0.f, 0.f, 0.f, 0.f};
            f32x4 acc = __builtin_amdgcn_mfma_f32_16x16x32_bf16(ah, bh[j], z, 0, 0, 0);
            acc = __builtin_amdgcn_mfma_f32_16x16x32_bf16(al, bh[j], acc, 0, 0, 0);
            acc = __builtin_amdgcn_mfma_f32_16x16x32_bf16(ah, bl[j], acc, 0, 0, 0);
            float e0 = __builtin_amdgcn_exp2f(acc[0]);
            float e1 = __builtin_amdgcn_exp2f(acc[1]);
            float e2 = __builtin_amdgcn_exp2f(acc[2]);
            float e3 = __builtin_amdgcn_exp2f(acc[3]);
            p[j] += (e0 + e1) + (e2 + e3);
        }
    }
    // reduce over the 4 q-quarters (column r fixed)
#pragma unroll
    for (int j = 0; j < TILES; ++j) {
        p[j] += __shfl_xor(p[j], 16, 64);
        p[j] += __shfl_xor(p[j], 32, 64);
    }
    if (lane < 16) {
#pragma unroll
        for (int j = 0; j < TILES; ++j)
            atomicAdd(&out[m0 + j * 16 + r], p[j]);
    }
}

// ---- fallback: fp32 VALU kernel (no workspace needed)
constexpr int MPT  = 2;
constexpr int MBLK = TPB * MPT;

__global__ __launch_bounds__(TPB) void ke_plain(
    const float* __restrict__ x, const float* __restrict__ samples,
    const float* __restrict__ weights, const float* __restrict__ sigma_p,
    const float* __restrict__ length_p, float* __restrict__ out,
    int M, int N, int nsplit, int chunk) {
    int mb = blockIdx.x / nsplit;
    int ns = blockIdx.x - mb * nsplit;
    int t  = threadIdx.x;
    int m0 = mb * MBLK + t;
    int m1 = m0 + TPB;
    int m0c = (m0 < M) ? m0 : 0;
    int m1c = (m1 < M) ? m1 : 0;

    v2f_ xaq[D / 2], xbq[D / 2];
    const v2f_* xp0 = reinterpret_cast<const v2f_*>(x + (size_t)m0c * D);
    const v2f_* xp1 = reinterpret_cast<const v2f_*>(x + (size_t)m1c * D);
#pragma unroll
    for (int qq = 0; qq < D / 2; ++qq) { xaq[qq] = xp0[qq]; xbq[qq] = xp1[qq]; }
#pragma unroll
    for (int qq = 0; qq < D / 2; ++qq) { asm("" : "+v"(xaq[qq])); asm("" : "+v"(xbq[qq])); }

    float l   = length_p[0];
    float c   = -0.5f * LOG2E_F / (l * l);
    float m2c = -2.f * c;
    float sg  = sigma_p[0];
    float sg2 = sg * sg;

    v2f_ qa = {0.f, 0.f}, qb = {0.f, 0.f};
#pragma unroll
    for (int qq = 0; qq < D / 2; ++qq) {
        qa = __builtin_elementwise_fma(xaq[qq], xaq[qq], qa);
        qb = __builtin_elementwise_fma(xbq[qq], xbq[qq], qb);
    }
    float cxa = c * (qa.x + qa.y);
    float cxb = c * (qb.x + qb.y);

    float acc0 = 0.f, acc1 = 0.f;
    int n0 = ns * chunk;
    int n1 = n0 + chunk;
    if (n1 > N) n1 = N;
#pragma unroll 2
    for (int n = n0; n < n1; ++n) {
        const v2f_* s2 = reinterpret_cast<const v2f_*>(samples + (size_t)n * D);
        v2f_ da = {0.f, 0.f}, db = {0.f, 0.f}, sq = {0.f, 0.f};
#pragma unroll
        for (int qq = 0; qq < D / 2; ++qq) {
            v2f_ sv = s2[qq];
            sq = __builtin_elementwise_fma(sv, sv, sq);
            da = __builtin_elementwise_fma(sv, xaq[qq], da);
            db = __builtin_elementwise_fma(sv, xbq[qq], db);
        }
        float cn = c * (sq.x + sq.y);
        float wn = sg2 * weights[n];
        float e0 = fmaf(m2c, da.x + da.y, cn);
        float e1 = fmaf(m2c, db.x + db.y, cn);
        acc0 = fmaf(wn, __builtin_amdgcn_exp2f(e0), acc0);
        acc1 = fmaf(wn, __builtin_amdgcn_exp2f(e1), acc1);
    }
    if (m0 < M) atomicAdd(&out[m0], acc0 * __builtin_amdgcn_exp2f(cxa));
    if (m1 < M) atomicAdd(&out[m1], acc1 * __builtin_amdgcn_exp2f(cxb));
}

extern "C" void kernel_launch(void* const* d_in, const int* in_sizes, int n_in,
                              void* d_out, int out_size, void* d_ws, size_t ws_size,
                              hipStream_t stream) {
    const float* x       = (const float*)d_in[0];
    const float* samples = (const float*)d_in[1];
    const float* weights = (const float*)d_in[2];
    const float* sigma_p = (const float*)d_in[3];
    const float* length_p= (const float*)d_in[4];
    float* out = (float*)d_out;

    int M = in_sizes[0] / D;
    int N = in_sizes[1] / D;

    // workspace layout (bytes): xhi, xlo, shi, slo (+ safety pad)
    size_t xhi_off = 0;
    size_t xlo_off = xhi_off + (size_t)M * KP * 2;
    size_t shi_off = xlo_off + (size_t)M * KP * 2;
    size_t slo_off = shi_off + (size_t)N * KP * 2;
    size_t need    = slo_off + (size_t)N * KP * 2 + (size_t)16 * KP * 2;

    int  MT = TILES * 16;  // 64 m per wave
    bool mfma_ok = ws_size >= need &&
                   (M % MT) == 0 && ((M / MT) % (TPB / 64)) == 0 &&
                   (N % 16) == 0 && ((N / 16) % NSPLIT) == 0 && out_size >= M;

    if (mfma_ok) {
        char* ws = (char*)d_ws;
        unsigned short* xhi = (unsigned short*)(ws + xhi_off);
        unsigned short* xlo = (unsigned short*)(ws + xlo_off);
        unsigned short* shi = (unsigned short*)(ws + shi_off);
        unsigned short* slo = (unsigned short*)(ws + slo_off);

        prep_all<<<dim3((M + N + TPB_PRE - 1) / TPB_PRE), dim3(TPB_PRE), 0, stream>>>(
            x, samples, weights, sigma_p, length_p, xhi, xlo, shi, slo, out, M, N);

        int waves  = (M / MT) * NSPLIT;           // 8192
        int blocks = waves / (TPB / 64);          // 2048
        ke_mfma<<<dim3(blocks), dim3(TPB), 0, stream>>>(
            xhi, xlo, shi, slo, out, M, N);
    } else {
        hipMemsetAsync(out, 0, (size_t)out_size * sizeof(float), stream);
        int mbcnt  = (M + MBLK - 1) / MBLK;
        int nsplit = 2048 / (mbcnt > 0 ? mbcnt : 1);
        if (nsplit < 1) nsplit = 1;
        if (nsplit > N) nsplit = N;
        int chunk = (N + nsplit - 1) / nsplit;
        ke_plain<<<dim3(mbcnt * nsplit), dim3(TPB), 0, stream>>>(
            x, samples, weights, sigma_p, length_p, out, M, N, nsplit, chunk);
    }
}